// Round 6
// baseline (330.515 us; speedup 1.0000x reference)
//
#include <hip/hip_runtime.h>

typedef unsigned short u16;
typedef unsigned int   u32;
typedef __bf16 bfv8 __attribute__((ext_vector_type(8)));   // MFMA A/B frag: 8 bf16
typedef float  f32x4 __attribute__((ext_vector_type(4)));  // MFMA C/D frag
typedef short  s16x4 __attribute__((ext_vector_type(4)));  // 16x16x16 bf16_1k frag

#define B_   2
#define T_   2048
#define D_   1024
#define H_   16
#define HKV_ 4
#define NQK  1280            // qkv buffer holds Q(1024) + K(256); V goes to vT
#define BT_  (B_*T_)
// q_gain fold also includes 1/sqrt(64)=0.125 and log2(e) (softmax in log2 domain)
#define QSCALE 0.18033688011112042f
#define L2_10K 0.41524101186092515f   // log2(10000)/32

__device__ __forceinline__ u16 f2bf(float f) {   // native RNE cvt
  __bf16 h = (__bf16)f; u16 s; __builtin_memcpy(&s, &h, 2); return s;
}

// async global->LDS, 16B per lane; LDS dst = wave-uniform base + lane*16 (m104)
__device__ __forceinline__ void load16(const u16* g, u16* l) {
  auto gp = (const __attribute__((address_space(1))) u32*)(uintptr_t)g;
  auto lp = (__attribute__((address_space(3))) u32*)(uintptr_t)l;
  __builtin_amdgcn_global_load_lds(gp, lp, 16, 0, 0);
}

// ---------------- fp32 -> bf16 converts ----------------
__global__ void conv_kernel(const float* __restrict__ src, u16* __restrict__ dst, int n) {
  int i = (blockIdx.x * 256 + threadIdx.x) * 4;
  if (i >= n) return;
  float4 v = *(const float4*)(src + i);
  ushort4 o; o.x = f2bf(v.x); o.y = f2bf(v.y); o.z = f2bf(v.z); o.w = f2bf(v.w);
  *(ushort4*)(dst + i) = o;
}
// all 4 weight matrices in one launch; dst = wqkv|wpb contiguous (2.5M halfs)
__global__ void conv_w_kernel(const float* __restrict__ wq, const float* __restrict__ wk,
                              const float* __restrict__ wv, const float* __restrict__ wp,
                              u16* __restrict__ dst) {
  int i = (blockIdx.x * 256 + threadIdx.x) * 4;
  const float* s; int off;
  if      (i < 1048576) { s = wq; off = i; }
  else if (i < 1310720) { s = wk; off = i - 1048576; }
  else if (i < 1572864) { s = wv; off = i - 1310720; }
  else                  { s = wp; off = i - 1572864; }
  float4 v = *(const float4*)(s + off);
  ushort4 o; o.x = f2bf(v.x); o.y = f2bf(v.y); o.z = f2bf(v.z); o.w = f2bf(v.w);
  *(ushort4*)(dst + i) = o;
}

// ---------------- bf16 GEMM, C = A(M,K) @ B(N,K)^T, m97-style ----------------
// MODE 0: f32 out ld=N.
// MODE 2: fused QKV epilogue — Q/K cols get RoPE (+q_gain*QSCALE on Q) applied
//         on fp32 accumulators; V cols scattered transposed to vT[b][kvh][d][t].
template<int MODE>
__global__ __launch_bounds__(256) void gemm_bt(const u16* __restrict__ A,
                                               const u16* __restrict__ Bm,
                                               void* __restrict__ C,
                                               u16* __restrict__ vT,
                                               const float* __restrict__ qg,
                                               int M, int N, int K) {
  __shared__ __align__(16) u16 As[128 * 32];
  __shared__ __align__(16) u16 Bs[128 * 32];
  const int tid  = threadIdx.x;
  const int wave = tid >> 6, lane = tid & 63;
  const int quad = lane >> 4, l16 = lane & 15;
  const int m0 = blockIdx.y * 128, n0 = blockIdx.x * 128;
  const int wm = (wave >> 1) * 64, wn = (wave & 1) * 64;
  const int lr = lane >> 2, lc = (lane & 3) * 8;

  f32x4 acc[4][4];
  for (int mi = 0; mi < 4; ++mi)
    for (int ni = 0; ni < 4; ++ni) acc[mi][ni] = (f32x4){0.f, 0.f, 0.f, 0.f};

  for (int kk = 0; kk < K; kk += 32) {
    __syncthreads();
    #pragma unroll
    for (int u = 0; u < 2; ++u) {
      const int c = wave * 2 + u;
      const int r = c * 16 + lr;
      load16(A  + (size_t)(m0 + r) * K + kk + lc, As + c * 512);
      load16(Bm + (size_t)(n0 + r) * K + kk + lc, Bs + c * 512);
    }
    __syncthreads();
    bfv8 af[4], bf_[4];
    #pragma unroll
    for (int i = 0; i < 4; ++i) af[i]  = *(const bfv8*)(As + (wm + i*16 + l16)*32 + 8*quad);
    #pragma unroll
    for (int i = 0; i < 4; ++i) bf_[i] = *(const bfv8*)(Bs + (wn + i*16 + l16)*32 + 8*quad);
    #pragma unroll
    for (int mi = 0; mi < 4; ++mi)
      #pragma unroll
      for (int ni = 0; ni < 4; ++ni)
        acc[mi][ni] = __builtin_amdgcn_mfma_f32_16x16x32_bf16(af[mi], bf_[ni], acc[mi][ni], 0, 0, 0);
  }

  // C/D layout: row = 4*quad + reg, col = l16 (+16*ni +wn +n0)
  if (MODE == 0) {
    for (int mi = 0; mi < 4; ++mi)
      for (int ni = 0; ni < 4; ++ni)
        for (int r = 0; r < 4; ++r)
          ((float*)C)[(size_t)(m0 + wm + mi*16 + 4*quad + r) * N + n0 + wn + ni*16 + l16]
            = acc[mi][ni][r];
  } else {
    const int colbase = n0 + wn;                 // 64-aligned => exactly one head
    if (colbase < NQK) {                         // Q or K head: apply RoPE here
      const bool isQ = colbase < 1024;
      const float gain = isQ ? qg[colbase >> 6] * QSCALE : 1.0f;
      // lane's head-internal cols: j0=l16 (ni 0/2 pair), j1=l16+16 (ni 1/3 pair)
      const float inv0 = exp2f(-(float)l16 * L2_10K);
      const float inv1 = exp2f(-(float)(l16 + 16) * L2_10K);
      for (int mi = 0; mi < 4; ++mi) {
        const int rowg = m0 + wm + mi*16 + 4*quad;
        u16* dst = (u16*)C + (size_t)rowg * NQK + colbase + l16;
        #pragma unroll
        for (int r = 0; r < 4; ++r) {
          const int t = (rowg + r) & (T_ - 1);
          float s0, c0, s1, c1;
          sincosf((float)t * inv0, &s0, &c0);
          sincosf((float)t * inv1, &s1, &c1);
          const float x1a = acc[mi][0][r], x2a = acc[mi][2][r];
          const float x1b = acc[mi][1][r], x2b = acc[mi][3][r];
          u16* drow = dst + (size_t)r * NQK;
          drow[0]  = f2bf((x1a*c0 - x2a*s0) * gain);
          drow[16] = f2bf((x1b*c1 - x2b*s1) * gain);
          drow[32] = f2bf((x1a*s0 + x2a*c0) * gain);
          drow[48] = f2bf((x1b*s1 + x2b*c1) * gain);
        }
      }
    } else {              // V region -> transposed vT[b][kvh][d][t]
      for (int mi = 0; mi < 4; ++mi)
        for (int ni = 0; ni < 4; ++ni) {
          const int dd  = colbase + ni*16 + l16 - NQK;
          const int kvh = dd >> 6, d = dd & 63;
          const int rowg = m0 + wm + mi*16 + 4*quad;
          const int bb = rowg >> 11, t = rowg & (T_ - 1);
          ushort4 w4;
          w4.x = f2bf(acc[mi][ni][0]); w4.y = f2bf(acc[mi][ni][1]);
          w4.z = f2bf(acc[mi][ni][2]); w4.w = f2bf(acc[mi][ni][3]);
          *(ushort4*)(vT + ((size_t)((bb*HKV_ + kvh)*64 + d)) * T_ + t) = w4;
        }
    }
  }
}

// ---------------- Flash attention (causal, GQA, paired q-tiles, S^T trick) ----------------
// St = K Q^T (C-layout lane l16 = q-row, keys 4*quad+r) feeds P directly into
// PV (O^T = V^T P^T) as 16x16x16bf16_1k B-frags — no P LDS round-trip.
// Fixed-max softmax (M=0, log2 domain, scores O(1)-bounded).
// MERGED tile: K-frags and V-frags are strip-independent -> load once, feed
// both paired strips (A while kt<=qtA, B always). doA is block-uniform.
__device__ __forceinline__ void attn_tile(const u16* KB, const u16* VB,
                                          int l16, int quad,
                                          const bfv8* qA, const bfv8* qB, bool doA,
                                          float& psA, float& psB,
                                          f32x4 oA[4], f32x4 oB[4],
                                          int qColA, int qColB, int s0,
                                          bool diagA, bool diagB) {
  const int sw = l16 & 7;
  f32x4 stA[4], stB[4];
  #pragma unroll
  for (int ni = 0; ni < 4; ++ni) {
    const int row = ni*16 + l16;           // key row in K tile
    bfv8 k0 = *(const bfv8*)(KB + row*64 + 8*(quad ^ sw));
    bfv8 k1 = *(const bfv8*)(KB + row*64 + 8*((quad + 4) ^ sw));
    if (doA) {
      stA[ni] = __builtin_amdgcn_mfma_f32_16x16x32_bf16(k0, qA[0], (f32x4){0.f,0.f,0.f,0.f}, 0, 0, 0);
      stA[ni] = __builtin_amdgcn_mfma_f32_16x16x32_bf16(k1, qA[1], stA[ni], 0, 0, 0);
    }
    stB[ni] = __builtin_amdgcn_mfma_f32_16x16x32_bf16(k0, qB[0], (f32x4){0.f,0.f,0.f,0.f}, 0, 0, 0);
    stB[ni] = __builtin_amdgcn_mfma_f32_16x16x32_bf16(k1, qB[1], stB[ni], 0, 0, 0);
  }
  // mask + exp2 + per-lane row-sum + pack to bf16 B-frags (P^T in registers)
  s16x4 pbA[4], pbB[4];
  #pragma unroll
  for (int ni = 0; ni < 4; ++ni)
    #pragma unroll
    for (int r = 0; r < 4; ++r) {
      const int key = s0 + ni*16 + 4*quad + r;
      if (doA) {
        float v = stA[ni][r];
        if (diagA) v = (key <= qColA) ? v : -3.0e38f;
        const float p = exp2f(v);
        psA += p;
        pbA[ni][r] = (short)f2bf(p);
      }
      float v = stB[ni][r];
      if (diagB) v = (key <= qColB) ? v : -3.0e38f;
      const float p = exp2f(v);
      psB += p;
      pbB[ni][r] = (short)f2bf(p);
    }
  // O^T += V^T P^T  (shared V frags)
  #pragma unroll
  for (int ni = 0; ni < 4; ++ni) {
    const int vofs = 8*((2*ni + (quad >> 1)) ^ sw) + 4*(quad & 1);
    #pragma unroll
    for (int dt = 0; dt < 4; ++dt) {
      s16x4 va = *(const s16x4*)(VB + (dt*16 + l16)*64 + vofs);
      if (doA) oA[dt] = __builtin_amdgcn_mfma_f32_16x16x16bf16_1k(va, pbA[ni], oA[dt], 0, 0, 0);
      oB[dt] = __builtin_amdgcn_mfma_f32_16x16x16bf16_1k(va, pbB[ni], oB[dt], 0, 0, 0);
    }
  }
}

__global__ __launch_bounds__(256) void attn_kernel(const u16* __restrict__ qkv,
                                                   const u16* __restrict__ vT,
                                                   u16* __restrict__ o) {
  const int pr = blockIdx.x;            // pair id 0..15 -> q-tiles (pr, 31-pr)
  const int h  = blockIdx.y;
  const int b  = blockIdx.z;
  const int kvh = h >> 2;
  const int tid = threadIdx.x;
  const int wave = tid >> 6, lane = tid & 63;
  const int quad = lane >> 4, l16 = lane & 15;

  const int qtA = pr, qtB = 31 - pr;
  const int nk  = qtB + 1;

  __shared__ __align__(16) u16 Kl[2][64 * 64];
  __shared__ __align__(16) u16 Vl[2][64 * 64];

  const u16* qAp = qkv + (size_t)(b*T_ + qtA*64 + wave*16 + l16) * NQK + h*64 + 8*quad;
  const u16* qBp = qkv + (size_t)(b*T_ + qtB*64 + wave*16 + l16) * NQK + h*64 + 8*quad;
  const bfv8 qA[2] = { *(const bfv8*)qAp, *(const bfv8*)(qAp + 32) };
  const bfv8 qB[2] = { *(const bfv8*)qBp, *(const bfv8*)(qBp + 32) };

  float psA = 0.f, psB = 0.f;
  f32x4 oA[4], oB[4];
  #pragma unroll
  for (int d = 0; d < 4; ++d) oA[d] = oB[d] = (f32x4){0.f, 0.f, 0.f, 0.f};

  const int srow = lane >> 3, slot = lane & 7;
  const u16* Kg = qkv + (size_t)(b*T_) * NQK + 1024 + kvh*64;
  const u16* Vg = vT  + (size_t)((b*HKV_ + kvh) * 64) * T_;

  auto stage = [&](int kt, int buf) {
    const int s0 = kt * 64;
    #pragma unroll
    for (int u = 0; u < 2; ++u) {
      const int base = wave*16 + u*8;
      const int r  = base + srow;
      const int kc = slot ^ (r & 7);           // XOR chunk swizzle
      load16(Kg + (size_t)(s0 + r) * NQK + kc*8, Kl[buf] + base*64);
      load16(Vg + (size_t)r * T_ + s0 + kc*8,    Vl[buf] + base*64);
    }
  };

  stage(0, 0);
  const int qColA = qtA*64 + wave*16 + l16;    // lane's q row (strip A)
  const int qColB = qtB*64 + wave*16 + l16;
  for (int kt = 0; kt < nk; ++kt) {
    __syncthreads();                           // drains DMA(kt)
    if (kt + 1 < nk) stage(kt + 1, (kt + 1) & 1);
    attn_tile(Kl[kt & 1], Vl[kt & 1], l16, quad, qA, qB, kt <= qtA,
              psA, psB, oA, oB, qColA, qColB, kt*64, kt == qtA, kt == nk - 1);
  }

  // row sums: partials live on the 4 quads of each q-row lane
  #pragma unroll
  for (int off = 16; off < 64; off <<= 1) {
    psA += __shfl_xor(psA, off);
    psB += __shfl_xor(psB, off);
  }
  const float ivA = 1.0f / psA, ivB = 1.0f / psB;

  // O^T C-layout: col=l16=qrow, row=4*quad+r = d (+16*dt) -> pack 4 d's per store
  #pragma unroll
  for (int dt = 0; dt < 4; ++dt) {
    ushort4 wA, wB;
    wA.x = f2bf(oA[dt][0]*ivA); wA.y = f2bf(oA[dt][1]*ivA);
    wA.z = f2bf(oA[dt][2]*ivA); wA.w = f2bf(oA[dt][3]*ivA);
    wB.x = f2bf(oB[dt][0]*ivB); wB.y = f2bf(oB[dt][1]*ivB);
    wB.z = f2bf(oB[dt][2]*ivB); wB.w = f2bf(oB[dt][3]*ivB);
    *(ushort4*)(o + (size_t)(b*T_ + qColA) * D_ + h*64 + dt*16 + 4*quad) = wA;
    *(ushort4*)(o + (size_t)(b*T_ + qColB) * D_ + h*64 + dt*16 + 4*quad) = wB;
  }
}

// ---------------- launch ----------------
extern "C" void kernel_launch(void* const* d_in, const int* in_sizes, int n_in,
                              void* d_out, int out_size, void* d_ws, size_t ws_size,
                              hipStream_t stream) {
  const float* x  = (const float*)d_in[0];
  const float* Wq = (const float*)d_in[1];
  const float* Wk = (const float*)d_in[2];
  const float* Wv = (const float*)d_in[3];
  const float* Wp = (const float*)d_in[4];
  const float* qg = (const float*)d_in[5];

  u16* xb   = (u16*)d_ws;                        // 4096 x 1024 (reused as ob)
  u16* wqkv = xb   + (size_t)BT_ * D_;           // 1536 x 1024
  u16* wpb  = wqkv + (size_t)1536 * D_;          // 1024 x 1024 (contiguous after wqkv)
  u16* qkvb = wpb  + (size_t)D_ * D_;            // 4096 x 1280 (Q|K)
  u16* vT   = qkvb + (size_t)BT_ * NQK;          // [2][4][64][2048]
  u16* ob   = xb;

  conv_kernel<<<dim3((BT_*D_/4 + 255)/256), dim3(256), 0, stream>>>(x, xb, BT_*D_);
  conv_w_kernel<<<dim3(2560), dim3(256), 0, stream>>>(Wq, Wk, Wv, Wp, wqkv);

  gemm_bt<2><<<dim3(12, 32), dim3(256), 0, stream>>>(xb, wqkv, qkvb, vT, qg, BT_, 1536, D_);
  attn_kernel<<<dim3(16, H_, B_), dim3(256), 0, stream>>>(qkvb, vT, ob);
  gemm_bt<0><<<dim3(8, 32), dim3(256), 0, stream>>>(ob, wpb, d_out, (u16*)nullptr, nullptr, BT_, D_, D_);
}

// Round 7
// 208.737 us; speedup vs baseline: 1.5834x; 1.5834x over previous
//
#include <hip/hip_runtime.h>

typedef unsigned short u16;
typedef unsigned int   u32;
typedef __bf16 bfv8 __attribute__((ext_vector_type(8)));   // MFMA A/B frag: 8 bf16
typedef float  f32x4 __attribute__((ext_vector_type(4)));  // MFMA C/D frag
typedef short  s16x4 __attribute__((ext_vector_type(4)));  // 16x16x16 bf16_1k frag

#define B_   2
#define T_   2048
#define D_   1024
#define H_   16
#define HKV_ 4
#define NQK  1280            // qkv buffer holds Q(1024) + K(256); V goes to vT
#define BT_  (B_*T_)
// q_gain fold also includes 1/sqrt(64)=0.125 and log2(e) (softmax in log2 domain)
#define QSCALE 0.18033688011112042f
#define L2_10K 0.41524101186092515f   // log2(10000)/32
#define I2PI   0.15915494309189535f   // 1/(2*pi) — HW trig input is revolutions

__device__ __forceinline__ u16 f2bf(float f) {   // native RNE cvt
  __bf16 h = (__bf16)f; u16 s; __builtin_memcpy(&s, &h, 2); return s;
}

// async global->LDS, 16B per lane; LDS dst = wave-uniform base + lane*16 (m104)
__device__ __forceinline__ void load16(const u16* g, u16* l) {
  auto gp = (const __attribute__((address_space(1))) u32*)(uintptr_t)g;
  auto lp = (__attribute__((address_space(3))) u32*)(uintptr_t)l;
  __builtin_amdgcn_global_load_lds(gp, lp, 16, 0, 0);
}

// HW trig: v_sin_f32/v_cos_f32 take revolutions; explicit fract reduction
__device__ __forceinline__ void hw_sincos_rev(float rev, float& s, float& c) {
  rev -= floorf(rev);                  // folds to v_fract_f32
  s = __builtin_amdgcn_sinf(rev);
  c = __builtin_amdgcn_cosf(rev);
}

// ---------------- fp32 -> bf16 converts ----------------
__global__ void conv_kernel(const float* __restrict__ src, u16* __restrict__ dst, int n) {
  int i = (blockIdx.x * 256 + threadIdx.x) * 4;
  if (i >= n) return;
  float4 v = *(const float4*)(src + i);
  ushort4 o; o.x = f2bf(v.x); o.y = f2bf(v.y); o.z = f2bf(v.z); o.w = f2bf(v.w);
  *(ushort4*)(dst + i) = o;
}
// all 4 weight matrices in one launch; dst = wqkv|wpb contiguous (2.5M halfs)
__global__ void conv_w_kernel(const float* __restrict__ wq, const float* __restrict__ wk,
                              const float* __restrict__ wv, const float* __restrict__ wp,
                              u16* __restrict__ dst) {
  int i = (blockIdx.x * 256 + threadIdx.x) * 4;
  const float* s; int off;
  if      (i < 1048576) { s = wq; off = i; }
  else if (i < 1310720) { s = wk; off = i - 1048576; }
  else if (i < 1572864) { s = wv; off = i - 1310720; }
  else                  { s = wp; off = i - 1572864; }
  float4 v = *(const float4*)(s + off);
  ushort4 o; o.x = f2bf(v.x); o.y = f2bf(v.y); o.z = f2bf(v.z); o.w = f2bf(v.w);
  *(ushort4*)(dst + i) = o;
}

// ---------------- bf16 GEMM, C = A(M,K) @ B(N,K)^T, m97-style ----------------
// MODE 0: f32 out ld=N.
// MODE 2: fused QKV epilogue — Q/K cols get RoPE (+q_gain*QSCALE on Q) applied
//         on fp32 accumulators (HW v_sin/v_cos, NOT libm sincosf — scratch!);
//         V cols scattered transposed to vT[b][kvh][d][t].
template<int MODE>
__global__ __launch_bounds__(256) void gemm_bt(const u16* __restrict__ A,
                                               const u16* __restrict__ Bm,
                                               void* __restrict__ C,
                                               u16* __restrict__ vT,
                                               const float* __restrict__ qg,
                                               int M, int N, int K) {
  __shared__ __align__(16) u16 As[128 * 32];
  __shared__ __align__(16) u16 Bs[128 * 32];
  const int tid  = threadIdx.x;
  const int wave = tid >> 6, lane = tid & 63;
  const int quad = lane >> 4, l16 = lane & 15;
  const int m0 = blockIdx.y * 128, n0 = blockIdx.x * 128;
  const int wm = (wave >> 1) * 64, wn = (wave & 1) * 64;
  const int lr = lane >> 2, lc = (lane & 3) * 8;

  f32x4 acc[4][4];
  for (int mi = 0; mi < 4; ++mi)
    for (int ni = 0; ni < 4; ++ni) acc[mi][ni] = (f32x4){0.f, 0.f, 0.f, 0.f};

  for (int kk = 0; kk < K; kk += 32) {
    __syncthreads();
    #pragma unroll
    for (int u = 0; u < 2; ++u) {
      const int c = wave * 2 + u;
      const int r = c * 16 + lr;
      load16(A  + (size_t)(m0 + r) * K + kk + lc, As + c * 512);
      load16(Bm + (size_t)(n0 + r) * K + kk + lc, Bs + c * 512);
    }
    __syncthreads();
    bfv8 af[4], bf_[4];
    #pragma unroll
    for (int i = 0; i < 4; ++i) af[i]  = *(const bfv8*)(As + (wm + i*16 + l16)*32 + 8*quad);
    #pragma unroll
    for (int i = 0; i < 4; ++i) bf_[i] = *(const bfv8*)(Bs + (wn + i*16 + l16)*32 + 8*quad);
    #pragma unroll
    for (int mi = 0; mi < 4; ++mi)
      #pragma unroll
      for (int ni = 0; ni < 4; ++ni)
        acc[mi][ni] = __builtin_amdgcn_mfma_f32_16x16x32_bf16(af[mi], bf_[ni], acc[mi][ni], 0, 0, 0);
  }

  // C/D layout: row = 4*quad + reg, col = l16 (+16*ni +wn +n0)
  if (MODE == 0) {
    #pragma unroll
    for (int mi = 0; mi < 4; ++mi)
      #pragma unroll
      for (int ni = 0; ni < 4; ++ni)
        #pragma unroll
        for (int r = 0; r < 4; ++r)
          ((float*)C)[(size_t)(m0 + wm + mi*16 + 4*quad + r) * N + n0 + wn + ni*16 + l16]
            = acc[mi][ni][r];
  } else {
    const int colbase = n0 + wn;                 // 64-aligned => exactly one head
    if (colbase < NQK) {                         // Q or K head: apply RoPE here
      const bool isQ = colbase < 1024;
      const float gain = isQ ? qg[colbase >> 6] * QSCALE : 1.0f;
      // lane's head-internal cols: j0=l16 (ni 0/2 pair), j1=l16+16 (ni 1/3 pair)
      const float inv0 = exp2f(-(float)l16 * L2_10K) * I2PI;          // rev/step
      const float inv1 = exp2f(-(float)(l16 + 16) * L2_10K) * I2PI;
      #pragma unroll
      for (int mi = 0; mi < 4; ++mi) {
        const int rowg = m0 + wm + mi*16 + 4*quad;
        u16* dst = (u16*)C + (size_t)rowg * NQK + colbase + l16;
        #pragma unroll
        for (int r = 0; r < 4; ++r) {
          const int t = (rowg + r) & (T_ - 1);
          float s0, c0, s1, c1;
          hw_sincos_rev((float)t * inv0, s0, c0);
          hw_sincos_rev((float)t * inv1, s1, c1);
          const float x1a = acc[mi][0][r], x2a = acc[mi][2][r];
          const float x1b = acc[mi][1][r], x2b = acc[mi][3][r];
          u16* drow = dst + (size_t)r * NQK;
          drow[0]  = f2bf((x1a*c0 - x2a*s0) * gain);
          drow[16] = f2bf((x1b*c1 - x2b*s1) * gain);
          drow[32] = f2bf((x1a*s0 + x2a*c0) * gain);
          drow[48] = f2bf((x1b*s1 + x2b*c1) * gain);
        }
      }
    } else {              // V region -> transposed vT[b][kvh][d][t]
      #pragma unroll
      for (int mi = 0; mi < 4; ++mi)
        #pragma unroll
        for (int ni = 0; ni < 4; ++ni) {
          const int dd  = colbase + ni*16 + l16 - NQK;
          const int kvh = dd >> 6, d = dd & 63;
          const int rowg = m0 + wm + mi*16 + 4*quad;
          const int bb = rowg >> 11, t = rowg & (T_ - 1);
          ushort4 w4;
          w4.x = f2bf(acc[mi][ni][0]); w4.y = f2bf(acc[mi][ni][1]);
          w4.z = f2bf(acc[mi][ni][2]); w4.w = f2bf(acc[mi][ni][3]);
          *(ushort4*)(vT + ((size_t)((bb*HKV_ + kvh)*64 + d)) * T_ + t) = w4;
        }
    }
  }
}

// ---------------- Flash attention (causal, GQA, paired q-tiles, S^T trick) ----------------
// St = K Q^T (C-layout lane l16 = q-row, keys 4*quad+r) feeds P directly into
// PV (O^T = V^T P^T) as 16x16x16bf16_1k B-frags — no P LDS round-trip.
// Fixed-max softmax (M=0, log2 domain, scores O(1)-bounded).
// MERGED tile: K-frags and V-frags are strip-independent -> load once, feed
// both paired strips (A while kt<=qtA, B always). doA is block-uniform.
__device__ __forceinline__ void attn_tile(const u16* KB, const u16* VB,
                                          int l16, int quad,
                                          const bfv8* qA, const bfv8* qB, bool doA,
                                          float& psA, float& psB,
                                          f32x4 oA[4], f32x4 oB[4],
                                          int qColA, int qColB, int s0,
                                          bool diagA, bool diagB) {
  const int sw = l16 & 7;
  f32x4 stA[4], stB[4];
  #pragma unroll
  for (int ni = 0; ni < 4; ++ni) {
    const int row = ni*16 + l16;           // key row in K tile
    bfv8 k0 = *(const bfv8*)(KB + row*64 + 8*(quad ^ sw));
    bfv8 k1 = *(const bfv8*)(KB + row*64 + 8*((quad + 4) ^ sw));
    if (doA) {
      stA[ni] = __builtin_amdgcn_mfma_f32_16x16x32_bf16(k0, qA[0], (f32x4){0.f,0.f,0.f,0.f}, 0, 0, 0);
      stA[ni] = __builtin_amdgcn_mfma_f32_16x16x32_bf16(k1, qA[1], stA[ni], 0, 0, 0);
    }
    stB[ni] = __builtin_amdgcn_mfma_f32_16x16x32_bf16(k0, qB[0], (f32x4){0.f,0.f,0.f,0.f}, 0, 0, 0);
    stB[ni] = __builtin_amdgcn_mfma_f32_16x16x32_bf16(k1, qB[1], stB[ni], 0, 0, 0);
  }
  // mask + exp2 + per-lane row-sum + pack to bf16 B-frags (P^T in registers)
  s16x4 pbA[4], pbB[4];
  #pragma unroll
  for (int ni = 0; ni < 4; ++ni)
    #pragma unroll
    for (int r = 0; r < 4; ++r) {
      const int key = s0 + ni*16 + 4*quad + r;
      if (doA) {
        float v = stA[ni][r];
        if (diagA) v = (key <= qColA) ? v : -3.0e38f;
        const float p = exp2f(v);
        psA += p;
        pbA[ni][r] = (short)f2bf(p);
      }
      float v = stB[ni][r];
      if (diagB) v = (key <= qColB) ? v : -3.0e38f;
      const float p = exp2f(v);
      psB += p;
      pbB[ni][r] = (short)f2bf(p);
    }
  // O^T += V^T P^T  (shared V frags)
  #pragma unroll
  for (int ni = 0; ni < 4; ++ni) {
    const int vofs = 8*((2*ni + (quad >> 1)) ^ sw) + 4*(quad & 1);
    #pragma unroll
    for (int dt = 0; dt < 4; ++dt) {
      s16x4 va = *(const s16x4*)(VB + (dt*16 + l16)*64 + vofs);
      if (doA) oA[dt] = __builtin_amdgcn_mfma_f32_16x16x16bf16_1k(va, pbA[ni], oA[dt], 0, 0, 0);
      oB[dt] = __builtin_amdgcn_mfma_f32_16x16x16bf16_1k(va, pbB[ni], oB[dt], 0, 0, 0);
    }
  }
}

__global__ __launch_bounds__(256) void attn_kernel(const u16* __restrict__ qkv,
                                                   const u16* __restrict__ vT,
                                                   u16* __restrict__ o) {
  const int pr = blockIdx.x;            // pair id 0..15 -> q-tiles (pr, 31-pr)
  const int h  = blockIdx.y;
  const int b  = blockIdx.z;
  const int kvh = h >> 2;
  const int tid = threadIdx.x;
  const int wave = tid >> 6, lane = tid & 63;
  const int quad = lane >> 4, l16 = lane & 15;

  const int qtA = pr, qtB = 31 - pr;
  const int nk  = qtB + 1;

  __shared__ __align__(16) u16 Kl[2][64 * 64];
  __shared__ __align__(16) u16 Vl[2][64 * 64];

  const u16* qAp = qkv + (size_t)(b*T_ + qtA*64 + wave*16 + l16) * NQK + h*64 + 8*quad;
  const u16* qBp = qkv + (size_t)(b*T_ + qtB*64 + wave*16 + l16) * NQK + h*64 + 8*quad;
  const bfv8 qA[2] = { *(const bfv8*)qAp, *(const bfv8*)(qAp + 32) };
  const bfv8 qB[2] = { *(const bfv8*)qBp, *(const bfv8*)(qBp + 32) };

  float psA = 0.f, psB = 0.f;
  f32x4 oA[4], oB[4];
  #pragma unroll
  for (int d = 0; d < 4; ++d) oA[d] = oB[d] = (f32x4){0.f, 0.f, 0.f, 0.f};

  const int srow = lane >> 3, slot = lane & 7;
  const u16* Kg = qkv + (size_t)(b*T_) * NQK + 1024 + kvh*64;
  const u16* Vg = vT  + (size_t)((b*HKV_ + kvh) * 64) * T_;

  auto stage = [&](int kt, int buf) {
    const int s0 = kt * 64;
    #pragma unroll
    for (int u = 0; u < 2; ++u) {
      const int base = wave*16 + u*8;
      const int r  = base + srow;
      const int kc = slot ^ (r & 7);           // XOR chunk swizzle
      load16(Kg + (size_t)(s0 + r) * NQK + kc*8, Kl[buf] + base*64);
      load16(Vg + (size_t)r * T_ + s0 + kc*8,    Vl[buf] + base*64);
    }
  };

  stage(0, 0);
  const int qColA = qtA*64 + wave*16 + l16;    // lane's q row (strip A)
  const int qColB = qtB*64 + wave*16 + l16;
  for (int kt = 0; kt < nk; ++kt) {
    __syncthreads();                           // drains DMA(kt)
    if (kt + 1 < nk) stage(kt + 1, (kt + 1) & 1);
    attn_tile(Kl[kt & 1], Vl[kt & 1], l16, quad, qA, qB, kt <= qtA,
              psA, psB, oA, oB, qColA, qColB, kt*64, kt == qtA, kt == nk - 1);
  }

  // row sums: partials live on the 4 quads of each q-row lane
  #pragma unroll
  for (int off = 16; off < 64; off <<= 1) {
    psA += __shfl_xor(psA, off);
    psB += __shfl_xor(psB, off);
  }
  const float ivA = 1.0f / psA, ivB = 1.0f / psB;

  // O^T C-layout: col=l16=qrow, row=4*quad+r = d (+16*dt) -> pack 4 d's per store
  #pragma unroll
  for (int dt = 0; dt < 4; ++dt) {
    ushort4 wA, wB;
    wA.x = f2bf(oA[dt][0]*ivA); wA.y = f2bf(oA[dt][1]*ivA);
    wA.z = f2bf(oA[dt][2]*ivA); wA.w = f2bf(oA[dt][3]*ivA);
    wB.x = f2bf(oB[dt][0]*ivB); wB.y = f2bf(oB[dt][1]*ivB);
    wB.z = f2bf(oB[dt][2]*ivB); wB.w = f2bf(oB[dt][3]*ivB);
    *(ushort4*)(o + (size_t)(b*T_ + qColA) * D_ + h*64 + dt*16 + 4*quad) = wA;
    *(ushort4*)(o + (size_t)(b*T_ + qColB) * D_ + h*64 + dt*16 + 4*quad) = wB;
  }
}

// ---------------- launch ----------------
extern "C" void kernel_launch(void* const* d_in, const int* in_sizes, int n_in,
                              void* d_out, int out_size, void* d_ws, size_t ws_size,
                              hipStream_t stream) {
  const float* x  = (const float*)d_in[0];
  const float* Wq = (const float*)d_in[1];
  const float* Wk = (const float*)d_in[2];
  const float* Wv = (const float*)d_in[3];
  const float* Wp = (const float*)d_in[4];
  const float* qg = (const float*)d_in[5];

  u16* xb   = (u16*)d_ws;                        // 4096 x 1024 (reused as ob)
  u16* wqkv = xb   + (size_t)BT_ * D_;           // 1536 x 1024
  u16* wpb  = wqkv + (size_t)1536 * D_;          // 1024 x 1024 (contiguous after wqkv)
  u16* qkvb = wpb  + (size_t)D_ * D_;            // 4096 x 1280 (Q|K)
  u16* vT   = qkvb + (size_t)BT_ * NQK;          // [2][4][64][2048]
  u16* ob   = xb;

  conv_kernel<<<dim3((BT_*D_/4 + 255)/256), dim3(256), 0, stream>>>(x, xb, BT_*D_);
  conv_w_kernel<<<dim3(2560), dim3(256), 0, stream>>>(Wq, Wk, Wv, Wp, wqkv);

  gemm_bt<2><<<dim3(12, 32), dim3(256), 0, stream>>>(xb, wqkv, qkvb, vT, qg, BT_, 1536, D_);
  attn_kernel<<<dim3(16, H_, B_), dim3(256), 0, stream>>>(qkvb, vT, ob);
  gemm_bt<0><<<dim3(8, 32), dim3(256), 0, stream>>>(ob, wpb, d_out, (u16*)nullptr, nullptr, BT_, D_, D_);
}

// Round 8
// 174.483 us; speedup vs baseline: 1.8943x; 1.1963x over previous
//
#include <hip/hip_runtime.h>

typedef unsigned short u16;
typedef unsigned int   u32;
typedef __bf16 bfv8 __attribute__((ext_vector_type(8)));   // MFMA A/B frag: 8 bf16
typedef float  f32x4 __attribute__((ext_vector_type(4)));  // MFMA C/D frag
typedef short  s16x4 __attribute__((ext_vector_type(4)));  // 16x16x16 bf16_1k frag

#define B_   2
#define T_   2048
#define D_   1024
#define H_   16
#define HKV_ 4
#define NQK  1280            // qkv buffer holds Q(1024) + K(256); V goes to vT
#define BT_  (B_*T_)
// q_gain fold also includes 1/sqrt(64)=0.125 and log2(e) (softmax in log2 domain)
#define QSCALE 0.18033688011112042f
#define L2_10K 0.41524101186092515f   // log2(10000)/32
#define I2PI   0.15915494309189535f   // 1/(2*pi) — HW trig input is revolutions

__device__ __forceinline__ u16 f2bf(float f) {   // native RNE cvt
  __bf16 h = (__bf16)f; u16 s; __builtin_memcpy(&s, &h, 2); return s;
}

// async global->LDS, 16B per lane; LDS dst = wave-uniform base + lane*16 (m104)
__device__ __forceinline__ void load16(const u16* g, u16* l) {
  auto gp = (const __attribute__((address_space(1))) u32*)(uintptr_t)g;
  auto lp = (__attribute__((address_space(3))) u32*)(uintptr_t)l;
  __builtin_amdgcn_global_load_lds(gp, lp, 16, 0, 0);
}

// HW trig: v_sin_f32/v_cos_f32 take revolutions; explicit fract reduction
__device__ __forceinline__ void hw_sincos_rev(float rev, float& s, float& c) {
  rev -= floorf(rev);                  // folds to v_fract_f32
  s = __builtin_amdgcn_sinf(rev);
  c = __builtin_amdgcn_cosf(rev);
}

// ---------------- fp32 -> bf16 converts ----------------
__global__ void conv_kernel(const float* __restrict__ src, u16* __restrict__ dst, int n) {
  int i = (blockIdx.x * 256 + threadIdx.x) * 4;
  if (i >= n) return;
  float4 v = *(const float4*)(src + i);
  ushort4 o; o.x = f2bf(v.x); o.y = f2bf(v.y); o.z = f2bf(v.z); o.w = f2bf(v.w);
  *(ushort4*)(dst + i) = o;
}
// all 4 weight matrices in one launch; dst = wqkv|wpb contiguous (2.5M halfs)
__global__ void conv_w_kernel(const float* __restrict__ wq, const float* __restrict__ wk,
                              const float* __restrict__ wv, const float* __restrict__ wp,
                              u16* __restrict__ dst) {
  int i = (blockIdx.x * 256 + threadIdx.x) * 4;
  const float* s; int off;
  if      (i < 1048576) { s = wq; off = i; }
  else if (i < 1310720) { s = wk; off = i - 1048576; }
  else if (i < 1572864) { s = wv; off = i - 1310720; }
  else                  { s = wp; off = i - 1572864; }
  float4 v = *(const float4*)(s + off);
  ushort4 o; o.x = f2bf(v.x); o.y = f2bf(v.y); o.z = f2bf(v.z); o.w = f2bf(v.w);
  *(ushort4*)(dst + i) = o;
}

// ---------------- bf16 GEMM, C = A(M,K) @ B(N,K)^T, m97-style ----------------
// MODE 0: f32 out ld=N.
// MODE 2: fused QKV epilogue — Q/K cols get RoPE (+q_gain*QSCALE on Q) applied
//         on fp32 accumulators (HW v_sin/v_cos, NOT libm sincosf — scratch!);
//         V cols scattered transposed to vT[b][kvh][d][t].
template<int MODE>
__global__ __launch_bounds__(256) void gemm_bt(const u16* __restrict__ A,
                                               const u16* __restrict__ Bm,
                                               void* __restrict__ C,
                                               u16* __restrict__ vT,
                                               const float* __restrict__ qg,
                                               int M, int N, int K) {
  __shared__ __align__(16) u16 As[128 * 32];
  __shared__ __align__(16) u16 Bs[128 * 32];
  const int tid  = threadIdx.x;
  const int wave = tid >> 6, lane = tid & 63;
  const int quad = lane >> 4, l16 = lane & 15;
  const int m0 = blockIdx.y * 128, n0 = blockIdx.x * 128;
  const int wm = (wave >> 1) * 64, wn = (wave & 1) * 64;
  const int lr = lane >> 2, lc = (lane & 3) * 8;

  f32x4 acc[4][4];
  for (int mi = 0; mi < 4; ++mi)
    for (int ni = 0; ni < 4; ++ni) acc[mi][ni] = (f32x4){0.f, 0.f, 0.f, 0.f};

  for (int kk = 0; kk < K; kk += 32) {
    __syncthreads();
    #pragma unroll
    for (int u = 0; u < 2; ++u) {
      const int c = wave * 2 + u;
      const int r = c * 16 + lr;
      load16(A  + (size_t)(m0 + r) * K + kk + lc, As + c * 512);
      load16(Bm + (size_t)(n0 + r) * K + kk + lc, Bs + c * 512);
    }
    __syncthreads();
    bfv8 af[4], bf_[4];
    #pragma unroll
    for (int i = 0; i < 4; ++i) af[i]  = *(const bfv8*)(As + (wm + i*16 + l16)*32 + 8*quad);
    #pragma unroll
    for (int i = 0; i < 4; ++i) bf_[i] = *(const bfv8*)(Bs + (wn + i*16 + l16)*32 + 8*quad);
    #pragma unroll
    for (int mi = 0; mi < 4; ++mi)
      #pragma unroll
      for (int ni = 0; ni < 4; ++ni)
        acc[mi][ni] = __builtin_amdgcn_mfma_f32_16x16x32_bf16(af[mi], bf_[ni], acc[mi][ni], 0, 0, 0);
  }

  // C/D layout: row = 4*quad + reg, col = l16 (+16*ni +wn +n0)
  if (MODE == 0) {
    #pragma unroll
    for (int mi = 0; mi < 4; ++mi)
      #pragma unroll
      for (int ni = 0; ni < 4; ++ni)
        #pragma unroll
        for (int r = 0; r < 4; ++r)
          ((float*)C)[(size_t)(m0 + wm + mi*16 + 4*quad + r) * N + n0 + wn + ni*16 + l16]
            = acc[mi][ni][r];
  } else {
    const int colbase = n0 + wn;                 // 64-aligned => exactly one head
    if (colbase < NQK) {                         // Q or K head: apply RoPE here
      const bool isQ = colbase < 1024;
      const float gain = isQ ? qg[colbase >> 6] * QSCALE : 1.0f;
      // lane's head-internal cols: j0=l16 (ni 0/2 pair), j1=l16+16 (ni 1/3 pair)
      const float inv0 = exp2f(-(float)l16 * L2_10K) * I2PI;          // rev/step
      const float inv1 = exp2f(-(float)(l16 + 16) * L2_10K) * I2PI;
      #pragma unroll
      for (int mi = 0; mi < 4; ++mi) {
        const int rowg = m0 + wm + mi*16 + 4*quad;
        u16* dst = (u16*)C + (size_t)rowg * NQK + colbase + l16;
        #pragma unroll
        for (int r = 0; r < 4; ++r) {
          const int t = (rowg + r) & (T_ - 1);
          float s0, c0, s1, c1;
          hw_sincos_rev((float)t * inv0, s0, c0);
          hw_sincos_rev((float)t * inv1, s1, c1);
          const float x1a = acc[mi][0][r], x2a = acc[mi][2][r];
          const float x1b = acc[mi][1][r], x2b = acc[mi][3][r];
          u16* drow = dst + (size_t)r * NQK;
          drow[0]  = f2bf((x1a*c0 - x2a*s0) * gain);
          drow[16] = f2bf((x1b*c1 - x2b*s1) * gain);
          drow[32] = f2bf((x1a*s0 + x2a*c0) * gain);
          drow[48] = f2bf((x1b*s1 + x2b*c1) * gain);
        }
      }
    } else {              // V region -> transposed vT[b][kvh][d][t]
      #pragma unroll
      for (int mi = 0; mi < 4; ++mi)
        #pragma unroll
        for (int ni = 0; ni < 4; ++ni) {
          const int dd  = colbase + ni*16 + l16 - NQK;
          const int kvh = dd >> 6, d = dd & 63;
          const int rowg = m0 + wm + mi*16 + 4*quad;
          const int bb = rowg >> 11, t = rowg & (T_ - 1);
          ushort4 w4;
          w4.x = f2bf(acc[mi][ni][0]); w4.y = f2bf(acc[mi][ni][1]);
          w4.z = f2bf(acc[mi][ni][2]); w4.w = f2bf(acc[mi][ni][3]);
          *(ushort4*)(vT + ((size_t)((bb*HKV_ + kvh)*64 + d)) * T_ + t) = w4;
        }
    }
  }
}

// ---------------- Flash attention (causal, GQA, paired q-tiles, S^T trick) ----------------
// St = K Q^T (C-layout lane l16 = q-row, keys 4*quad+r) feeds P directly into
// PV (O^T = V^T P^T) as 16x16x16bf16_1k B-frags — no P LDS round-trip.
// Fixed-max softmax (M=0, log2 domain, scores O(1)-bounded).
// COMPILE-TIME strip/diag specialization (R7 lesson: runtime bools get
// if-converted inside unrolled loops -> dead strip's exp2/MFMA chain executes).
template<bool DOA, bool DIAGA, bool DIAGB>
__device__ __forceinline__ void attn_tile(const u16* KB, const u16* VB,
                                          int l16, int quad,
                                          const bfv8* qA, const bfv8* qB,
                                          float& psA, float& psB,
                                          f32x4 oA[4], f32x4 oB[4],
                                          int qColA, int qColB, int s0) {
  const int sw = l16 & 7;
  f32x4 stA[4], stB[4];
  #pragma unroll
  for (int ni = 0; ni < 4; ++ni) {
    const int row = ni*16 + l16;           // key row in K tile
    bfv8 k0 = *(const bfv8*)(KB + row*64 + 8*(quad ^ sw));
    bfv8 k1 = *(const bfv8*)(KB + row*64 + 8*((quad + 4) ^ sw));
    if (DOA) {
      stA[ni] = __builtin_amdgcn_mfma_f32_16x16x32_bf16(k0, qA[0], (f32x4){0.f,0.f,0.f,0.f}, 0, 0, 0);
      stA[ni] = __builtin_amdgcn_mfma_f32_16x16x32_bf16(k1, qA[1], stA[ni], 0, 0, 0);
    }
    stB[ni] = __builtin_amdgcn_mfma_f32_16x16x32_bf16(k0, qB[0], (f32x4){0.f,0.f,0.f,0.f}, 0, 0, 0);
    stB[ni] = __builtin_amdgcn_mfma_f32_16x16x32_bf16(k1, qB[1], stB[ni], 0, 0, 0);
  }
  // mask + exp2 + per-lane row-sum + pack to bf16 B-frags (P^T in registers)
  s16x4 pbA[4], pbB[4];
  #pragma unroll
  for (int ni = 0; ni < 4; ++ni)
    #pragma unroll
    for (int r = 0; r < 4; ++r) {
      const int key = s0 + ni*16 + 4*quad + r;
      if (DOA) {
        float v = stA[ni][r];
        if (DIAGA) v = (key <= qColA) ? v : -3.0e38f;
        const float p = __builtin_amdgcn_exp2f(v);
        psA += p;
        pbA[ni][r] = (short)f2bf(p);
      }
      float v = stB[ni][r];
      if (DIAGB) v = (key <= qColB) ? v : -3.0e38f;
      const float p = __builtin_amdgcn_exp2f(v);
      psB += p;
      pbB[ni][r] = (short)f2bf(p);
    }
  // O^T += V^T P^T  (shared V frags)
  #pragma unroll
  for (int ni = 0; ni < 4; ++ni) {
    const int vofs = 8*((2*ni + (quad >> 1)) ^ sw) + 4*(quad & 1);
    #pragma unroll
    for (int dt = 0; dt < 4; ++dt) {
      s16x4 va = *(const s16x4*)(VB + (dt*16 + l16)*64 + vofs);
      if (DOA) oA[dt] = __builtin_amdgcn_mfma_f32_16x16x16bf16_1k(va, pbA[ni], oA[dt], 0, 0, 0);
      oB[dt] = __builtin_amdgcn_mfma_f32_16x16x16bf16_1k(va, pbB[ni], oB[dt], 0, 0, 0);
    }
  }
}

__global__ __launch_bounds__(256) void attn_kernel(const u16* __restrict__ qkv,
                                                   const u16* __restrict__ vT,
                                                   u16* __restrict__ o) {
  const int pr = blockIdx.x;            // pair id 0..15 -> q-tiles (pr, 31-pr)
  const int h  = blockIdx.y;
  const int b  = blockIdx.z;
  const int kvh = h >> 2;
  const int tid = threadIdx.x;
  const int wave = tid >> 6, lane = tid & 63;
  const int quad = lane >> 4, l16 = lane & 15;

  const int qtA = pr, qtB = 31 - pr;
  const int nk  = qtB + 1;              // qtA < qtB always (pr in 0..15)

  __shared__ __align__(16) u16 Kl[2][64 * 64];
  __shared__ __align__(16) u16 Vl[2][64 * 64];

  const u16* qAp = qkv + (size_t)(b*T_ + qtA*64 + wave*16 + l16) * NQK + h*64 + 8*quad;
  const u16* qBp = qkv + (size_t)(b*T_ + qtB*64 + wave*16 + l16) * NQK + h*64 + 8*quad;
  const bfv8 qA[2] = { *(const bfv8*)qAp, *(const bfv8*)(qAp + 32) };
  const bfv8 qB[2] = { *(const bfv8*)qBp, *(const bfv8*)(qBp + 32) };

  float psA = 0.f, psB = 0.f;
  f32x4 oA[4], oB[4];
  #pragma unroll
  for (int d = 0; d < 4; ++d) oA[d] = oB[d] = (f32x4){0.f, 0.f, 0.f, 0.f};

  const int srow = lane >> 3, slot = lane & 7;
  const u16* Kg = qkv + (size_t)(b*T_) * NQK + 1024 + kvh*64;
  const u16* Vg = vT  + (size_t)((b*HKV_ + kvh) * 64) * T_;

  auto stage = [&](int kt, int buf) {
    const int s0 = kt * 64;
    #pragma unroll
    for (int u = 0; u < 2; ++u) {
      const int base = wave*16 + u*8;
      const int r  = base + srow;
      const int kc = slot ^ (r & 7);           // XOR chunk swizzle
      load16(Kg + (size_t)(s0 + r) * NQK + kc*8, Kl[buf] + base*64);
      load16(Vg + (size_t)r * T_ + s0 + kc*8,    Vl[buf] + base*64);
    }
  };

  stage(0, 0);
  const int qColA = qtA*64 + wave*16 + l16;    // lane's q row (strip A)
  const int qColB = qtB*64 + wave*16 + l16;

  // Phase 1: kt in [0, qtA) — both strips, no diag
  for (int kt = 0; kt < qtA; ++kt) {
    __syncthreads();
    stage(kt + 1, (kt + 1) & 1);
    attn_tile<true, false, false>(Kl[kt & 1], Vl[kt & 1], l16, quad, qA, qB,
                                  psA, psB, oA, oB, qColA, qColB, kt*64);
  }
  // kt = qtA — both strips, diag on A (qtA < nk-1 always)
  {
    const int kt = qtA;
    __syncthreads();
    stage(kt + 1, (kt + 1) & 1);
    attn_tile<true, true, false>(Kl[kt & 1], Vl[kt & 1], l16, quad, qA, qB,
                                 psA, psB, oA, oB, qColA, qColB, kt*64);
  }
  // Phase 2: kt in (qtA, nk-1) — strip B only
  for (int kt = qtA + 1; kt < nk - 1; ++kt) {
    __syncthreads();
    stage(kt + 1, (kt + 1) & 1);
    attn_tile<false, false, false>(Kl[kt & 1], Vl[kt & 1], l16, quad, qA, qB,
                                   psA, psB, oA, oB, qColA, qColB, kt*64);
  }
  // kt = nk-1 — strip B, diag
  {
    const int kt = nk - 1;
    __syncthreads();
    attn_tile<false, false, true>(Kl[kt & 1], Vl[kt & 1], l16, quad, qA, qB,
                                  psA, psB, oA, oB, qColA, qColB, kt*64);
  }

  // row sums: partials live on the 4 quads of each q-row lane
  #pragma unroll
  for (int off = 16; off < 64; off <<= 1) {
    psA += __shfl_xor(psA, off);
    psB += __shfl_xor(psB, off);
  }
  const float ivA = 1.0f / psA, ivB = 1.0f / psB;

  // O^T C-layout: col=l16=qrow, row=4*quad+r = d (+16*dt) -> pack 4 d's per store
  #pragma unroll
  for (int dt = 0; dt < 4; ++dt) {
    ushort4 wA, wB;
    wA.x = f2bf(oA[dt][0]*ivA); wA.y = f2bf(oA[dt][1]*ivA);
    wA.z = f2bf(oA[dt][2]*ivA); wA.w = f2bf(oA[dt][3]*ivA);
    wB.x = f2bf(oB[dt][0]*ivB); wB.y = f2bf(oB[dt][1]*ivB);
    wB.z = f2bf(oB[dt][2]*ivB); wB.w = f2bf(oB[dt][3]*ivB);
    *(ushort4*)(o + (size_t)(b*T_ + qColA) * D_ + h*64 + dt*16 + 4*quad) = wA;
    *(ushort4*)(o + (size_t)(b*T_ + qColB) * D_ + h*64 + dt*16 + 4*quad) = wB;
  }
}

// ---------------- launch ----------------
extern "C" void kernel_launch(void* const* d_in, const int* in_sizes, int n_in,
                              void* d_out, int out_size, void* d_ws, size_t ws_size,
                              hipStream_t stream) {
  const float* x  = (const float*)d_in[0];
  const float* Wq = (const float*)d_in[1];
  const float* Wk = (const float*)d_in[2];
  const float* Wv = (const float*)d_in[3];
  const float* Wp = (const float*)d_in[4];
  const float* qg = (const float*)d_in[5];

  u16* xb   = (u16*)d_ws;                        // 4096 x 1024 (reused as ob)
  u16* wqkv = xb   + (size_t)BT_ * D_;           // 1536 x 1024
  u16* wpb  = wqkv + (size_t)1536 * D_;          // 1024 x 1024 (contiguous after wqkv)
  u16* qkvb = wpb  + (size_t)D_ * D_;            // 4096 x 1280 (Q|K)
  u16* vT   = qkvb + (size_t)BT_ * NQK;          // [2][4][64][2048]
  u16* ob   = xb;

  conv_kernel<<<dim3((BT_*D_/4 + 255)/256), dim3(256), 0, stream>>>(x, xb, BT_*D_);
  conv_w_kernel<<<dim3(2560), dim3(256), 0, stream>>>(Wq, Wk, Wv, Wp, wqkv);

  gemm_bt<2><<<dim3(12, 32), dim3(256), 0, stream>>>(xb, wqkv, qkvb, vT, qg, BT_, 1536, D_);
  attn_kernel<<<dim3(16, H_, B_), dim3(256), 0, stream>>>(qkvb, vT, ob);
  gemm_bt<0><<<dim3(8, 32), dim3(256), 0, stream>>>(ob, wpb, d_out, (u16*)nullptr, nullptr, BT_, D_, D_);
}